// Round 1
// baseline (6326.213 us; speedup 1.0000x reference)
//
#include <hip/hip_runtime.h>
#include <math.h>

#define DSTATE 512
#define DIN    256
#define DOUTD  256
#define BATCH  16
#define SEQ    4096
#define CHUNK  64
#define NCHUNK 64            // SEQ/CHUNK
#define ROWS   (NCHUNK*BATCH) // 1024

struct Scalars {
    double logacc;   // offset 0
    float  s2;       // offset 8
    float  kscale;   // offset 12
};

// ---------------------------------------------------------------------------
// Generic tiled fp32 GEMM. OP: 0 = NN (C=A@B), 1 = NT (C=A@B^T), 2 = TN (C=A^T@B)
// Requires M%64==0, N%64==0, K%16==0. C = scale*(op(A)@op(B)) + beta*C.
// SKEWA: A row r is remapped to r + (r>>12)  (for pre_states stride 4097).
// ---------------------------------------------------------------------------
template<int OP, bool SKEWA>
__global__ __launch_bounds__(256)
void gemm64(int M, int N, int K,
            const float* __restrict__ A, int lda,
            const float* __restrict__ B, int ldb,
            float* __restrict__ C, int ldc,
            const float* __restrict__ scale_ptr, float beta)
{
    __shared__ float As[16][68];
    __shared__ float Bs[16][68];
    const int row0 = blockIdx.x * 64;
    const int col0 = blockIdx.y * 64;
    const int tid  = threadIdx.x;
    const int tx   = tid & 15, ty = tid >> 4;
    float acc[4][4] = {};

    for (int k0 = 0; k0 < K; k0 += 16) {
        if (OP == 0 || OP == 1) {            // A row-major M x K
#pragma unroll
            for (int i = 0; i < 4; i++) {
                int e = tid + i * 256;
                int mm = e >> 4, kk = e & 15;
                int r = row0 + mm;
                long rr = SKEWA ? (long)(r + (r >> 12)) : (long)r;
                As[kk][mm] = A[rr * lda + k0 + kk];
            }
        } else {                              // TN: A is K x M
#pragma unroll
            for (int i = 0; i < 4; i++) {
                int e = tid + i * 256;
                int mm = e & 63, kk = e >> 6;
                As[kk][mm] = A[(long)(k0 + kk) * lda + row0 + mm];
            }
        }
        if (OP == 0 || OP == 2) {             // B row-major K x N
#pragma unroll
            for (int i = 0; i < 4; i++) {
                int e = tid + i * 256;
                int nn = e & 63, kk = e >> 6;
                Bs[kk][nn] = B[(long)(k0 + kk) * ldb + col0 + nn];
            }
        } else {                              // NT: B is N x K
#pragma unroll
            for (int i = 0; i < 4; i++) {
                int e = tid + i * 256;
                int nn = e >> 4, kk = e & 15;
                Bs[kk][nn] = B[(long)(col0 + nn) * ldb + k0 + kk];
            }
        }
        __syncthreads();
#pragma unroll
        for (int kk = 0; kk < 16; kk++) {
            float4 a4 = *(const float4*)&As[kk][ty * 4];
            float4 b4 = *(const float4*)&Bs[kk][tx * 4];
            float a[4] = {a4.x, a4.y, a4.z, a4.w};
            float b[4] = {b4.x, b4.y, b4.z, b4.w};
#pragma unroll
            for (int i = 0; i < 4; i++)
#pragma unroll
                for (int j = 0; j < 4; j++)
                    acc[i][j] += a[i] * b[j];
        }
        __syncthreads();
    }

    float scale = scale_ptr ? *scale_ptr : 1.0f;
#pragma unroll
    for (int i = 0; i < 4; i++) {
#pragma unroll
        for (int j = 0; j < 4; j++) {
            long r = row0 + ty * 4 + i;
            long c = col0 + tx * 4 + j;
            long idx = r * ldc + c;
            float v = scale * acc[i][j];
            if (beta != 0.0f) v += beta * C[idx];
            C[idx] = v;
        }
    }
}

// ---------------------------------------------------------------------------
// Scan step: Xout = Xin @ A^T + Bu_rows(step) ; optionally store into states.
// Rows r = k*16 + b (k chunk, b batch). 32x32 tile, 2x2 per thread.
// Xin == nullptr -> treated as zero.
// ---------------------------------------------------------------------------
__global__ __launch_bounds__(256)
void step_kernel(const float* __restrict__ Xin,
                 const float* __restrict__ Amat,
                 const float* __restrict__ Bu,
                 int stepi,
                 float* __restrict__ Xout,
                 float* __restrict__ states)
{
    __shared__ float As[16][36];
    __shared__ float Bs[16][36];
    const int row0 = blockIdx.x * 32;
    const int col0 = blockIdx.y * 32;
    const int tid  = threadIdx.x;
    const int tx   = tid & 15, ty = tid >> 4;
    float acc[2][2] = {};

    if (Xin) {
        for (int k0 = 0; k0 < 512; k0 += 16) {
#pragma unroll
            for (int i = 0; i < 2; i++) {
                int e = tid + i * 256;
                int mm = e >> 4, kk = e & 15;
                As[kk][mm] = Xin[(long)(row0 + mm) * 512 + k0 + kk];
            }
#pragma unroll
            for (int i = 0; i < 2; i++) {
                int e = tid + i * 256;
                int nn = e >> 4, kk = e & 15;
                Bs[kk][nn] = Amat[(long)(col0 + nn) * 512 + k0 + kk];
            }
            __syncthreads();
#pragma unroll
            for (int kk = 0; kk < 16; kk++) {
                float a0 = As[kk][ty * 2], a1 = As[kk][ty * 2 + 1];
                float b0 = Bs[kk][tx * 2], b1 = Bs[kk][tx * 2 + 1];
                acc[0][0] += a0 * b0; acc[0][1] += a0 * b1;
                acc[1][0] += a1 * b0; acc[1][1] += a1 * b1;
            }
            __syncthreads();
        }
    }

#pragma unroll
    for (int i = 0; i < 2; i++) {
        int r = row0 + ty * 2 + i;
        int k = r >> 4, b = r & 15;
        int t = k * CHUNK + stepi;
        const float* burow = Bu + ((long)b * SEQ + t) * 512;
        float* xorow = Xout + (long)r * 512;
        float* strow = states ? (states + ((long)b * (SEQ + 1) + t + 1) * 512) : nullptr;
#pragma unroll
        for (int j = 0; j < 2; j++) {
            int c = col0 + tx * 2 + j;
            float v = acc[i][j] + burow[c];
            xorow[c] = v;
            if (strow) strow[c] = v;
        }
    }
}

// ---------------------------------------------------------------------------
// Pass-2 boundary step: xb_next[b,n] = sum_kk xb_k[b,kk]*A64[n,kk] + Gk[b,n]
// A64T is A64 transposed (A64T[kk*512+n] = A64[n*512+kk]). 32 blocks x 256.
// ---------------------------------------------------------------------------
__global__ __launch_bounds__(256)
void pass2_step(const float* __restrict__ xb_k,
                const float* __restrict__ A64T,
                const float* __restrict__ Gk,
                float* __restrict__ xb_next)
{
    int gid = blockIdx.x * 256 + threadIdx.x;   // 0..8191
    int b = gid >> 9, n = gid & 511;
    const float* xrow = xb_k + (long)b * 512;
    float acc = 0.f;
#pragma unroll 8
    for (int kk = 0; kk < 512; kk++)
        acc += xrow[kk] * A64T[(long)kk * 512 + n];
    xb_next[gid] = acc + Gk[gid];
}

__global__ __launch_bounds__(256)
void transpose512(const float* __restrict__ in, float* __restrict__ out)
{
    __shared__ float t[32][33];
    int bx = blockIdx.x * 32, by = blockIdx.y * 32;
    int lx = threadIdx.x & 31, ly = threadIdx.x >> 5;  // 32 x 8
    for (int i = 0; i < 32; i += 8)
        t[ly + i][lx] = in[(long)(by + ly + i) * 512 + bx + lx];
    __syncthreads();
    for (int i = 0; i < 32; i += 8)
        out[(long)(bx + ly + i) * 512 + by + lx] = t[lx][ly + i];
}

__global__ __launch_bounds__(256)
void trace_update(const float* __restrict__ P, int n, float w, int first, Scalars* sc)
{
    __shared__ float red[256];
    float s = 0.f;
    for (int i = threadIdx.x; i < n; i += 256) s += P[(long)i * n + i];
    red[threadIdx.x] = s;
    __syncthreads();
    for (int o = 128; o > 0; o >>= 1) {
        if (threadIdx.x < o) red[threadIdx.x] += red[threadIdx.x + o];
        __syncthreads();
    }
    if (threadIdx.x == 0) {
        float t = red[0];
        double la = first ? 0.0 : sc->logacc;
        la += (double)w * log((double)t);
        sc->logacc = la;
        sc->s2 = 1.0f / (t * t);
    }
}

__global__ __launch_bounds__(64)
void finalize_sigma(Scalars* sc)
{
    if (threadIdx.x == 0) {
        double sigma = exp(0.5 * sc->logacc);
        if (sigma < 1e-5) sigma = 1e-5;
        sc->kscale = (float)(1.0 / (sigma + 0.002));
    }
}

__global__ __launch_bounds__(256)
void newton_init(const float* __restrict__ S, float* __restrict__ X)
{
    int gid = blockIdx.x * 256 + threadIdx.x;   // 262144
    int i = gid >> 9, j = gid & 511;
    X[gid] = ((i == j) ? 2.0f : 0.0f) - S[gid];
}

__global__ __launch_bounds__(256)
void newton_update(float* __restrict__ X, const float* __restrict__ Z)
{
    int gid = blockIdx.x * 256 + threadIdx.x;
    X[gid] = 2.0f * X[gid] - Z[gid];
}

__global__ __launch_bounds__(256)
void copy_kernel(const float* __restrict__ in, float* __restrict__ out, int n)
{
    int gid = blockIdx.x * 256 + threadIdx.x;
    if (gid < n) out[gid] = in[gid];
}

__global__ __launch_bounds__(256)
void scatter_bounds(const float* __restrict__ xb, float* __restrict__ states)
{
    int gid = blockIdx.x * 256 + threadIdx.x;   // 65*16*512 = 532480
    int n = gid & 511, r = gid >> 9;
    int k = r >> 4, b = r & 15;
    states[((long)b * (SEQ + 1) + (long)k * CHUNK) * 512 + n] = xb[gid];
}

// ---------------------------------------------------------------------------
extern "C" void kernel_launch(void* const* d_in, const int* in_sizes, int n_in,
                              void* d_out, int out_size, void* d_ws, size_t ws_size,
                              hipStream_t stream)
{
    const float* u     = (const float*)d_in[0];  // (16,4096,256)
    const float* state = (const float*)d_in[1];  // (16,512)
    const float* S     = (const float*)d_in[2];  // (512,512)
    const float* Kraw  = (const float*)d_in[3];  // (768,768)

    float* out    = (float*)d_out;                         // (16,4096,256)
    float* states = out + (long)BATCH * SEQ * DOUTD;       // (16,4097,512)

    char* w8 = (char*)d_ws;
    Scalars* sc = (Scalars*)w8;
    float* base = (float*)(w8 + 64);
    float* X    = base;               // 512^2  (becomes Sinv)
    float* Y    = X    + 262144;
    float* Z    = Y    + 262144;
    float* T1   = Z    + 262144;
    float* Amat = T1   + 262144;
    float* ApA  = Amat + 262144;
    float* ApB  = ApA  + 262144;
    float* A64T = ApB  + 262144;
    float* Bmat = A64T + 262144;      // 512x256
    float* Cmat = Bmat + 131072;      // 256x512
    float* Bu   = Cmat + 131072;      // 16*4096*512 = 33554432
    float* P0   = Bu;                 // overlay: 768^2 sigma ping
    float* P1   = Bu + 589824;        // overlay: 768^2 sigma pong
    float* Z0   = Bu + 33554432;      // 1024x512
    float* Z1   = Z0 + 524288;
    float* G    = Z1 + 524288;        // 1024x512
    float* xb   = G  + 524288;        // 65*16 x 512 = 532480

    dim3 blk(256);

    // ---- Phase 0: sigma = ||K_raw||_2 via trace-normalized squaring ----
    gemm64<2, false><<<dim3(12, 12), blk, 0, stream>>>(768, 768, 768,
        Kraw, 768, Kraw, 768, P0, 768, nullptr, 0.f);
    trace_update<<<1, blk, 0, stream>>>(P0, 768, 1.0f, 1, sc);
    {
        float* pa = P0; float* pb = P1; float wgt = 0.5f;
        for (int j = 1; j <= 12; j++) {
            gemm64<0, false><<<dim3(12, 12), blk, 0, stream>>>(768, 768, 768,
                pa, 768, pa, 768, pb, 768, &sc->s2, 0.f);
            trace_update<<<1, blk, 0, stream>>>(pb, 768, wgt, 0, sc);
            wgt *= 0.5f;
            float* t = pa; pa = pb; pb = t;
        }
    }
    finalize_sigma<<<1, 64, 0, stream>>>(sc);

    // ---- Phase 1: Sinv via Newton (X0 = 2I - S, 5 iters) ----
    newton_init<<<1024, blk, 0, stream>>>(S, X);
    for (int it = 0; it < 5; it++) {
        gemm64<0, false><<<dim3(8, 8), blk, 0, stream>>>(512, 512, 512,
            S, 512, X, 512, Y, 512, nullptr, 0.f);
        gemm64<0, false><<<dim3(8, 8), blk, 0, stream>>>(512, 512, 512,
            X, 512, Y, 512, Z, 512, nullptr, 0.f);
        newton_update<<<1024, blk, 0, stream>>>(X, Z);
    }

    // ---- Phase 2: A = kscale*Sinv@K11@S, B = kscale*Sinv@K12, C = kscale*K21@S
    gemm64<0, false><<<dim3(8, 8), blk, 0, stream>>>(512, 512, 512,
        X, 512, Kraw, 768, T1, 512, &sc->kscale, 0.f);            // T1 = kscale*Sinv@K11
    gemm64<0, false><<<dim3(8, 8), blk, 0, stream>>>(512, 512, 512,
        T1, 512, S, 512, Amat, 512, nullptr, 0.f);                // A = T1@S
    gemm64<0, false><<<dim3(8, 4), blk, 0, stream>>>(512, 256, 512,
        X, 512, Kraw + 512, 768, Bmat, 256, &sc->kscale, 0.f);    // B
    gemm64<0, false><<<dim3(4, 8), blk, 0, stream>>>(256, 512, 512,
        Kraw + (long)512 * 768, 768, S, 512, Cmat, 512, &sc->kscale, 0.f); // C

    // ---- Phase 3: A^64 via repeated squaring, then transpose ----
    gemm64<0, false><<<dim3(8, 8), blk, 0, stream>>>(512, 512, 512,
        Amat, 512, Amat, 512, ApA, 512, nullptr, 0.f);            // A^2
    gemm64<0, false><<<dim3(8, 8), blk, 0, stream>>>(512, 512, 512,
        ApA, 512, ApA, 512, ApB, 512, nullptr, 0.f);              // A^4
    gemm64<0, false><<<dim3(8, 8), blk, 0, stream>>>(512, 512, 512,
        ApB, 512, ApB, 512, ApA, 512, nullptr, 0.f);              // A^8
    gemm64<0, false><<<dim3(8, 8), blk, 0, stream>>>(512, 512, 512,
        ApA, 512, ApA, 512, ApB, 512, nullptr, 0.f);              // A^16
    gemm64<0, false><<<dim3(8, 8), blk, 0, stream>>>(512, 512, 512,
        ApB, 512, ApB, 512, ApA, 512, nullptr, 0.f);              // A^32
    gemm64<0, false><<<dim3(8, 8), blk, 0, stream>>>(512, 512, 512,
        ApA, 512, ApA, 512, ApB, 512, nullptr, 0.f);              // A^64
    transpose512<<<dim3(16, 16), blk, 0, stream>>>(ApB, A64T);

    // ---- Phase 4: Bu = u @ B^T  (65536x512, K=256) ----
    gemm64<1, false><<<dim3(1024, 8), blk, 0, stream>>>(65536, 512, 256,
        u, 256, Bmat, 256, Bu, 512, nullptr, 0.f);

    // ---- Phase 5 (pass 1): zero-init within-chunk scans -> G (chunk aggregates)
    {
        float* pin = nullptr;
        float* pout = Z0;
        for (int i = 0; i < 64; i++) {
            float* dst = (i == 63) ? G : pout;
            step_kernel<<<dim3(32, 16), blk, 0, stream>>>(pin, Amat, Bu, i, dst, nullptr);
            pin = dst;
            pout = (pin == Z0) ? Z1 : Z0;
        }
    }

    // ---- Phase 6 (pass 2): sequential boundary chain with A^64 ----
    copy_kernel<<<32, blk, 0, stream>>>(state, xb, BATCH * 512);
    for (int k = 0; k < 64; k++) {
        pass2_step<<<32, blk, 0, stream>>>(xb + (long)k * 16 * 512, A64T,
                                           G + (long)k * 16 * 512,
                                           xb + (long)(k + 1) * 16 * 512);
    }
    scatter_bounds<<<2080, blk, 0, stream>>>(xb, states);

    // ---- Phase 7 (pass 3): within-chunk scans from true boundaries, store states
    {
        float* pin = xb;   // rows 0..1023 are boundaries k=0..63
        float* pout = Z0;
        for (int i = 0; i < 63; i++) {
            step_kernel<<<dim3(32, 16), blk, 0, stream>>>(pin, Amat, Bu, i, pout, states);
            pin = pout;
            pout = (pin == Z0) ? Z1 : Z0;
        }
    }

    // ---- Phase 8: output = pre_states @ C^T + kscale*(u @ K22^T) ----
    gemm64<1, true><<<dim3(1024, 4), blk, 0, stream>>>(65536, 256, 512,
        states, 512, Cmat, 512, out, 256, nullptr, 0.f);
    gemm64<1, false><<<dim3(1024, 4), blk, 0, stream>>>(65536, 256, 256,
        u, 256, Kraw + (long)512 * 768 + 512, 768, out, 256, &sc->kscale, 1.0f);
}

// Round 2
// 4517.807 us; speedup vs baseline: 1.4003x; 1.4003x over previous
//
#include <hip/hip_runtime.h>
#include <math.h>

#define BATCH  16
#define SEQ    4096
#define CHUNK  64

typedef __attribute__((ext_vector_type(8))) short short8;
typedef __attribute__((ext_vector_type(4))) float f32x4;

struct Scalars {
    double logacc;
    float  s2;
    float  kscale;
};

// ---- bf16 split helpers (round-to-nearest-even) ----
__device__ __forceinline__ unsigned short f2bf(float x) {
    unsigned u = __builtin_bit_cast(unsigned, x);
    unsigned r = u + 0x7fffu + ((u >> 16) & 1u);
    return (unsigned short)(r >> 16);
}
__device__ __forceinline__ float bf2f(unsigned short h) {
    unsigned u = ((unsigned)h) << 16;
    return __builtin_bit_cast(float, u);
}

// ---------------------------------------------------------------------------
// Split-bf16 MFMA NT GEMM: C[M,N] = scale * (A[M,K] @ B[N,K]^T) (+ C if BETA)
// A,B fp32 in global; hi/lo split done at LDS staging. M%128==0, N%128==0,
// K%32==0. Tile 128x128, 256 threads (4 waves 2x2, each 64x64 via 4x4 MFMA).
// SKEWA: A row r -> r + (r>>12)  (pre_states stride-4097 view).
// LDS layout per plane: slot = (subtile*4 + kquad), entry = slot*136 + m*8 + j
// (shorts); slot stride 272B keeps b128 alignment, <=2-way bank aliasing.
// ---------------------------------------------------------------------------
template<bool SKEWA, bool BETA>
__global__ __launch_bounds__(256, 2)
void mfma_nt(int M, int N, int K,
             const float* __restrict__ A, int lda,
             const float* __restrict__ B, int ldb,
             float* __restrict__ C, int ldc,
             const float* __restrict__ scale_ptr)
{
    __shared__ unsigned short Ah[32 * 136], Al[32 * 136];
    __shared__ unsigned short Bh[32 * 136], Bl[32 * 136];
    const int t    = threadIdx.x;
    const int lane = t & 63, w = t >> 6;
    const int wr   = w >> 1, wc = w & 1;
    const int m15  = lane & 15, q = lane >> 4;
    const int row0 = blockIdx.x * 128, col0 = blockIdx.y * 128;

    const int kk = (t & 7) * 4;      // k offset within 32-tile (fp32 loader)
    const int lq = kk >> 3, j0 = kk & 7;
    const int r0 = t >> 3;           // base row (0..31), 4 sweeps of 32

    f32x4 zero = {0.f, 0.f, 0.f, 0.f};
    f32x4 acc[4][4];
#pragma unroll
    for (int i = 0; i < 4; i++)
#pragma unroll
        for (int j = 0; j < 4; j++) acc[i][j] = zero;

    for (int k0 = 0; k0 < K; k0 += 32) {
#pragma unroll
        for (int s = 0; s < 4; s++) {
            int r = r0 + 32 * s;
            long gr = row0 + r;
            if (SKEWA) gr += (gr >> 12);
            float4 v = *(const float4*)(A + gr * lda + k0 + kk);
            ushort4 hv, lv;
            hv.x = f2bf(v.x); lv.x = f2bf(v.x - bf2f(hv.x));
            hv.y = f2bf(v.y); lv.y = f2bf(v.y - bf2f(hv.y));
            hv.z = f2bf(v.z); lv.z = f2bf(v.z - bf2f(hv.z));
            hv.w = f2bf(v.w); lv.w = f2bf(v.w - bf2f(hv.w));
            int us = ((r >> 4) * 4 + lq) * 136 + (r & 15) * 8 + j0;
            *(ushort4*)&Ah[us] = hv;
            *(ushort4*)&Al[us] = lv;
        }
#pragma unroll
        for (int s = 0; s < 4; s++) {
            int r = r0 + 32 * s;
            float4 v = *(const float4*)(B + (long)(col0 + r) * ldb + k0 + kk);
            ushort4 hv, lv;
            hv.x = f2bf(v.x); lv.x = f2bf(v.x - bf2f(hv.x));
            hv.y = f2bf(v.y); lv.y = f2bf(v.y - bf2f(hv.y));
            hv.z = f2bf(v.z); lv.z = f2bf(v.z - bf2f(hv.z));
            hv.w = f2bf(v.w); lv.w = f2bf(v.w - bf2f(hv.w));
            int us = ((r >> 4) * 4 + lq) * 136 + (r & 15) * 8 + j0;
            *(ushort4*)&Bh[us] = hv;
            *(ushort4*)&Bl[us] = lv;
        }
        __syncthreads();

        short8 ah[4], al[4], bh[4], bl[4];
#pragma unroll
        for (int i = 0; i < 4; i++) {
            int slot = ((wr * 4 + i) * 4 + q) * 136 + m15 * 8;
            ah[i] = *(const short8*)&Ah[slot];
            al[i] = *(const short8*)&Al[slot];
        }
#pragma unroll
        for (int j = 0; j < 4; j++) {
            int slot = ((wc * 4 + j) * 4 + q) * 136 + m15 * 8;
            bh[j] = *(const short8*)&Bh[slot];
            bl[j] = *(const short8*)&Bl[slot];
        }
#pragma unroll
        for (int j = 0; j < 4; j++)
#pragma unroll
            for (int i = 0; i < 4; i++) {
                acc[i][j] = __builtin_amdgcn_mfma_f32_16x16x32_bf16(ah[i], bh[j], acc[i][j], 0, 0, 0);
                acc[i][j] = __builtin_amdgcn_mfma_f32_16x16x32_bf16(ah[i], bl[j], acc[i][j], 0, 0, 0);
                acc[i][j] = __builtin_amdgcn_mfma_f32_16x16x32_bf16(al[i], bh[j], acc[i][j], 0, 0, 0);
            }
        __syncthreads();
    }

    float scale = scale_ptr ? *scale_ptr : 1.0f;
#pragma unroll
    for (int i = 0; i < 4; i++) {
#pragma unroll
        for (int j = 0; j < 4; j++) {
            int row = row0 + 64 * wr + 16 * i + 4 * q;
            int col = col0 + 64 * wc + 16 * j + m15;
#pragma unroll
            for (int rr = 0; rr < 4; rr++) {
                long idx = (long)(row + rr) * ldc + col;
                float v = scale * acc[i][j][rr];
                if (BETA) v += C[idx];
                C[idx] = v;
            }
        }
    }
}

// ---------------------------------------------------------------------------
// Scan step (MFMA): Xout[1024,512] = Xin @ A^T + Bu_rows(step).
// A supplied as pre-split bf16 hi/lo planes (row-major [n][k], 512x512).
// Tile 32x64, grid (32,8)=256 blocks. Xin==nullptr -> zero (copy Bu).
// ---------------------------------------------------------------------------
__global__ __launch_bounds__(256)
void step_mfma(const float* __restrict__ Xin,
               const unsigned short* __restrict__ Ahig,
               const unsigned short* __restrict__ Alog,
               const float* __restrict__ Bu,
               int stepi,
               float* __restrict__ Xout,
               float* __restrict__ states)
{
    __shared__ unsigned short Xh[8 * 136], Xl[8 * 136];
    __shared__ unsigned short BhS[16 * 136], BlS[16 * 136];
    const int t    = threadIdx.x;
    const int lane = t & 63, w = t >> 6;
    const int wr   = w & 1, wc = w >> 1;
    const int m15  = lane & 15, q = lane >> 4;
    const int row0 = blockIdx.x * 32, col0 = blockIdx.y * 64;

    f32x4 zero = {0.f, 0.f, 0.f, 0.f};
    f32x4 acc[2] = {zero, zero};

    if (Xin) {
        const int kkA = (t & 7) * 4, qA = kkA >> 3, j0A = kkA & 7, rA = t >> 3;
        const int kkB = (t & 3) * 8, qB = kkB >> 3, rB = t >> 2;
        for (int k0 = 0; k0 < 512; k0 += 32) {
            {   // stage Xin tile (fp32 -> hi/lo)
                float4 v = *(const float4*)(Xin + (long)(row0 + rA) * 512 + k0 + kkA);
                ushort4 hv, lv;
                hv.x = f2bf(v.x); lv.x = f2bf(v.x - bf2f(hv.x));
                hv.y = f2bf(v.y); lv.y = f2bf(v.y - bf2f(hv.y));
                hv.z = f2bf(v.z); lv.z = f2bf(v.z - bf2f(hv.z));
                hv.w = f2bf(v.w); lv.w = f2bf(v.w - bf2f(hv.w));
                int us = ((rA >> 4) * 4 + qA) * 136 + (rA & 15) * 8 + j0A;
                *(ushort4*)&Xh[us] = hv;
                *(ushort4*)&Xl[us] = lv;
            }
            {   // stage A-matrix planes (already bf16)
                long off = (long)(col0 + rB) * 512 + k0 + kkB;
                uint4 hv = *(const uint4*)(Ahig + off);
                uint4 lv = *(const uint4*)(Alog + off);
                int us = ((rB >> 4) * 4 + qB) * 136 + (rB & 15) * 8;
                *(uint4*)&BhS[us] = hv;
                *(uint4*)&BlS[us] = lv;
            }
            __syncthreads();
            int sa = (wr * 4 + q) * 136 + m15 * 8;
            short8 xh = *(const short8*)&Xh[sa];
            short8 xl = *(const short8*)&Xl[sa];
#pragma unroll
            for (int jj = 0; jj < 2; jj++) {
                int sb = ((wc * 2 + jj) * 4 + q) * 136 + m15 * 8;
                short8 bh = *(const short8*)&BhS[sb];
                short8 bl = *(const short8*)&BlS[sb];
                acc[jj] = __builtin_amdgcn_mfma_f32_16x16x32_bf16(xh, bh, acc[jj], 0, 0, 0);
                acc[jj] = __builtin_amdgcn_mfma_f32_16x16x32_bf16(xh, bl, acc[jj], 0, 0, 0);
                acc[jj] = __builtin_amdgcn_mfma_f32_16x16x32_bf16(xl, bh, acc[jj], 0, 0, 0);
            }
            __syncthreads();
        }
    }

#pragma unroll
    for (int jj = 0; jj < 2; jj++) {
        int col = col0 + 32 * wc + 16 * jj + m15;
#pragma unroll
        for (int rr = 0; rr < 4; rr++) {
            int r = row0 + 16 * wr + 4 * q + rr;
            int k = r >> 4, b = r & 15;
            int tt = k * CHUNK + stepi;
            float v = acc[jj][rr] + Bu[((long)b * SEQ + tt) * 512 + col];
            Xout[(long)r * 512 + col] = v;
            if (states) states[((long)b * (SEQ + 1) + tt + 1) * 512 + col] = v;
        }
    }
}

// ---------------------------------------------------------------------------
// fp32 tiled GEMM (setup phases). OP: 0=NN, 1=NT, 2=TN.
// ---------------------------------------------------------------------------
template<int OP>
__global__ __launch_bounds__(256)
void gemm64(int M, int N, int K,
            const float* __restrict__ A, int lda,
            const float* __restrict__ B, int ldb,
            float* __restrict__ C, int ldc,
            const float* __restrict__ scale_ptr, float beta)
{
    __shared__ float As[16][68];
    __shared__ float Bs[16][68];
    const int row0 = blockIdx.x * 64;
    const int col0 = blockIdx.y * 64;
    const int tid  = threadIdx.x;
    const int tx   = tid & 15, ty = tid >> 4;
    float acc[4][4] = {};

    for (int k0 = 0; k0 < K; k0 += 16) {
        if (OP == 0 || OP == 1) {
#pragma unroll
            for (int i = 0; i < 4; i++) {
                int e = tid + i * 256;
                int mm = e >> 4, kkx = e & 15;
                As[kkx][mm] = A[(long)(row0 + mm) * lda + k0 + kkx];
            }
        } else {
#pragma unroll
            for (int i = 0; i < 4; i++) {
                int e = tid + i * 256;
                int mm = e & 63, kkx = e >> 6;
                As[kkx][mm] = A[(long)(k0 + kkx) * lda + row0 + mm];
            }
        }
        if (OP == 0 || OP == 2) {
#pragma unroll
            for (int i = 0; i < 4; i++) {
                int e = tid + i * 256;
                int nn = e & 63, kkx = e >> 6;
                Bs[kkx][nn] = B[(long)(k0 + kkx) * ldb + col0 + nn];
            }
        } else {
#pragma unroll
            for (int i = 0; i < 4; i++) {
                int e = tid + i * 256;
                int nn = e >> 4, kkx = e & 15;
                Bs[kkx][nn] = B[(long)(col0 + nn) * ldb + k0 + kkx];
            }
        }
        __syncthreads();
#pragma unroll
        for (int kkx = 0; kkx < 16; kkx++) {
            float4 a4 = *(const float4*)&As[kkx][ty * 4];
            float4 b4 = *(const float4*)&Bs[kkx][tx * 4];
            float a[4] = {a4.x, a4.y, a4.z, a4.w};
            float b[4] = {b4.x, b4.y, b4.z, b4.w};
#pragma unroll
            for (int i = 0; i < 4; i++)
#pragma unroll
                for (int j = 0; j < 4; j++)
                    acc[i][j] += a[i] * b[j];
        }
        __syncthreads();
    }

    float scale = scale_ptr ? *scale_ptr : 1.0f;
#pragma unroll
    for (int i = 0; i < 4; i++)
#pragma unroll
        for (int j = 0; j < 4; j++) {
            long r = row0 + ty * 4 + i;
            long c = col0 + tx * 4 + j;
            long idx = r * ldc + c;
            float v = scale * acc[i][j];
            if (beta != 0.0f) v += beta * C[idx];
            C[idx] = v;
        }
}

// ---------------------------------------------------------------------------
__global__ __launch_bounds__(256)
void pass2_step(const float* __restrict__ xb_k,
                const float* __restrict__ A64T,
                const float* __restrict__ Gk,
                float* __restrict__ xb_next)
{
    int gid = blockIdx.x * 256 + threadIdx.x;   // 0..8191
    int b = gid >> 9, n = gid & 511;
    const float* xrow = xb_k + (long)b * 512;
    float acc = 0.f;
#pragma unroll 8
    for (int kk = 0; kk < 512; kk++)
        acc += xrow[kk] * A64T[(long)kk * 512 + n];
    xb_next[gid] = acc + Gk[gid];
}

__global__ __launch_bounds__(256)
void transpose_sq(const float* __restrict__ in, float* __restrict__ out, int n)
{
    __shared__ float t[32][33];
    int bx = blockIdx.x * 32, by = blockIdx.y * 32;
    int lx = threadIdx.x & 31, ly = threadIdx.x >> 5;  // 32 x 8
    for (int i = 0; i < 32; i += 8)
        t[ly + i][lx] = in[(long)(by + ly + i) * n + bx + lx];
    __syncthreads();
    for (int i = 0; i < 32; i += 8)
        out[(long)(bx + ly + i) * n + by + lx] = t[lx][ly + i];
}

__global__ __launch_bounds__(256)
void trace_update(const float* __restrict__ P, int n, float wgt, int first, Scalars* sc)
{
    __shared__ float red[256];
    float s = 0.f;
    for (int i = threadIdx.x; i < n; i += 256) s += P[(long)i * n + i];
    red[threadIdx.x] = s;
    __syncthreads();
    for (int o = 128; o > 0; o >>= 1) {
        if (threadIdx.x < o) red[threadIdx.x] += red[threadIdx.x + o];
        __syncthreads();
    }
    if (threadIdx.x == 0) {
        float tr = red[0];
        double la = first ? 0.0 : sc->logacc;
        la += (double)wgt * log((double)tr);
        sc->logacc = la;
        sc->s2 = 1.0f / (tr * tr);
    }
}

__global__ __launch_bounds__(64)
void finalize_sigma(Scalars* sc)
{
    if (threadIdx.x == 0) {
        double sigma = exp(0.5 * sc->logacc);
        if (sigma < 1e-5) sigma = 1e-5;
        sc->kscale = (float)(1.0 / (sigma + 0.002));
    }
}

__global__ __launch_bounds__(256)
void newton_init(const float* __restrict__ S, float* __restrict__ X)
{
    int gid = blockIdx.x * 256 + threadIdx.x;
    int i = gid >> 9, j = gid & 511;
    X[gid] = ((i == j) ? 2.0f : 0.0f) - S[gid];
}

__global__ __launch_bounds__(256)
void newton_update(float* __restrict__ X, const float* __restrict__ Z)
{
    int gid = blockIdx.x * 256 + threadIdx.x;
    X[gid] = 2.0f * X[gid] - Z[gid];
}

__global__ __launch_bounds__(256)
void copy_kernel(const float* __restrict__ in, float* __restrict__ out, int n)
{
    int gid = blockIdx.x * 256 + threadIdx.x;
    if (gid < n) out[gid] = in[gid];
}

__global__ __launch_bounds__(256)
void convert_planes(const float* __restrict__ in,
                    unsigned short* __restrict__ hi,
                    unsigned short* __restrict__ lo, int n)
{
    int gid = blockIdx.x * 256 + threadIdx.x;
    if (gid < n) {
        float x = in[gid];
        unsigned short h = f2bf(x);
        hi[gid] = h;
        lo[gid] = f2bf(x - bf2f(h));
    }
}

__global__ __launch_bounds__(256)
void scatter_bounds(const float* __restrict__ xb, float* __restrict__ states)
{
    int gid = blockIdx.x * 256 + threadIdx.x;   // 65*16*512 = 532480
    int n = gid & 511, r = gid >> 9;
    int k = r >> 4, b = r & 15;
    states[((long)b * (SEQ + 1) + (long)k * CHUNK) * 512 + n] = xb[gid];
}

// ---------------------------------------------------------------------------
extern "C" void kernel_launch(void* const* d_in, const int* in_sizes, int n_in,
                              void* d_out, int out_size, void* d_ws, size_t ws_size,
                              hipStream_t stream)
{
    const float* u     = (const float*)d_in[0];  // (16,4096,256)
    const float* state = (const float*)d_in[1];  // (16,512)
    const float* S     = (const float*)d_in[2];  // (512,512)
    const float* Kraw  = (const float*)d_in[3];  // (768,768)

    float* out    = (float*)d_out;                         // (16,4096,256)
    float* states = out + (long)BATCH * SEQ * 256;         // (16,4097,512)

    char* w8 = (char*)d_ws;
    Scalars* sc = (Scalars*)w8;
    float* base = (float*)(w8 + 64);
    float* X    = base;               // 512^2 (becomes Sinv)
    float* Y    = X    + 262144;
    float* Z    = Y    + 262144;
    float* T1   = Z    + 262144;
    float* Amat = T1   + 262144;
    float* ApA  = Amat + 262144;
    float* ApB  = ApA  + 262144;
    float* A64T = ApB  + 262144;
    float* Bmat = A64T + 262144;      // 512x256
    float* Cmat = Bmat + 131072;      // 256x512
    float* Bu   = Cmat + 131072;      // 16*4096*512
    float* P0   = Bu;                 // overlay: 768^2 sigma ping
    float* P1   = Bu + 589824;        // overlay: 768^2 sigma pong
    float* Z0   = Bu + 33554432;      // 1024x512
    float* Z1   = Z0 + 524288;
    float* G    = Z1 + 524288;        // 1024x512
    float* xb   = G  + 524288;        // 65*16 x 512
    float* KT   = xb + 532480;        // 768x768
    unsigned short* Ahig = (unsigned short*)(KT + 589824);   // 512x512 bf16
    unsigned short* Alog = Ahig + 262144;                    // 512x512 bf16

    dim3 blk(256);

    // ---- Phase 0: sigma = ||K_raw||_2 via trace-normalized squaring (MFMA)
    transpose_sq<<<dim3(24, 24), blk, 0, stream>>>(Kraw, KT, 768);
    mfma_nt<false, false><<<dim3(6, 6), blk, 0, stream>>>(768, 768, 768,
        KT, 768, KT, 768, P0, 768, nullptr);                 // P0 = K^T K
    trace_update<<<1, blk, 0, stream>>>(P0, 768, 1.0f, 1, sc);
    {
        float* pa = P0; float* pb = P1; float wgt = 0.5f;
        for (int j = 1; j <= 12; j++) {
            mfma_nt<false, false><<<dim3(6, 6), blk, 0, stream>>>(768, 768, 768,
                pa, 768, pa, 768, pb, 768, &sc->s2);         // P symmetric -> NT ok
            trace_update<<<1, blk, 0, stream>>>(pb, 768, wgt, 0, sc);
            wgt *= 0.5f;
            float* tmp = pa; pa = pb; pb = tmp;
        }
    }
    finalize_sigma<<<1, 64, 0, stream>>>(sc);

    // ---- Phase 1: Sinv via Newton (X0 = 2I - S, 4 iters) ----
    newton_init<<<1024, blk, 0, stream>>>(S, X);
    for (int it = 0; it < 4; it++) {
        gemm64<0><<<dim3(8, 8), blk, 0, stream>>>(512, 512, 512,
            S, 512, X, 512, Y, 512, nullptr, 0.f);
        gemm64<0><<<dim3(8, 8), blk, 0, stream>>>(512, 512, 512,
            X, 512, Y, 512, Z, 512, nullptr, 0.f);
        newton_update<<<1024, blk, 0, stream>>>(X, Z);
    }

    // ---- Phase 2: A = kscale*Sinv@K11@S, B = kscale*Sinv@K12, C = kscale*K21@S
    gemm64<0><<<dim3(8, 8), blk, 0, stream>>>(512, 512, 512,
        X, 512, Kraw, 768, T1, 512, &sc->kscale, 0.f);
    gemm64<0><<<dim3(8, 8), blk, 0, stream>>>(512, 512, 512,
        T1, 512, S, 512, Amat, 512, nullptr, 0.f);
    gemm64<0><<<dim3(8, 4), blk, 0, stream>>>(512, 256, 512,
        X, 512, Kraw + 512, 768, Bmat, 256, &sc->kscale, 0.f);
    gemm64<0><<<dim3(4, 8), blk, 0, stream>>>(256, 512, 512,
        Kraw + (long)512 * 768, 768, S, 512, Cmat, 512, &sc->kscale, 0.f);

    // ---- Phase 3: A^64 via repeated squaring; transpose; bf16 planes ----
    gemm64<0><<<dim3(8, 8), blk, 0, stream>>>(512, 512, 512,
        Amat, 512, Amat, 512, ApA, 512, nullptr, 0.f);       // A^2
    gemm64<0><<<dim3(8, 8), blk, 0, stream>>>(512, 512, 512,
        ApA, 512, ApA, 512, ApB, 512, nullptr, 0.f);         // A^4
    gemm64<0><<<dim3(8, 8), blk, 0, stream>>>(512, 512, 512,
        ApB, 512, ApB, 512, ApA, 512, nullptr, 0.f);         // A^8
    gemm64<0><<<dim3(8, 8), blk, 0, stream>>>(512, 512, 512,
        ApA, 512, ApA, 512, ApB, 512, nullptr, 0.f);         // A^16
    gemm64<0><<<dim3(8, 8), blk, 0, stream>>>(512, 512, 512,
        ApB, 512, ApB, 512, ApA, 512, nullptr, 0.f);         // A^32
    gemm64<0><<<dim3(8, 8), blk, 0, stream>>>(512, 512, 512,
        ApA, 512, ApA, 512, ApB, 512, nullptr, 0.f);         // A^64
    transpose_sq<<<dim3(16, 16), blk, 0, stream>>>(ApB, A64T, 512);
    convert_planes<<<1024, blk, 0, stream>>>(Amat, Ahig, Alog, 262144);

    // ---- Phase 4: Bu = u @ B^T (65536x512, K=256) ----
    mfma_nt<false, false><<<dim3(512, 4), blk, 0, stream>>>(65536, 512, 256,
        u, 256, Bmat, 256, Bu, 512, nullptr);

    // ---- Phase 5 (pass 1): zero-init within-chunk scans -> G ----
    {
        float* pin = nullptr;
        float* pout = Z0;
        for (int i = 0; i < 64; i++) {
            float* dst = (i == 63) ? G : pout;
            step_mfma<<<dim3(32, 8), blk, 0, stream>>>(pin, Ahig, Alog, Bu, i, dst, nullptr);
            pin = dst;
            pout = (pin == Z0) ? Z1 : Z0;
        }
    }

    // ---- Phase 6 (pass 2): sequential boundary chain with A^64 ----
    copy_kernel<<<32, blk, 0, stream>>>(state, xb, BATCH * 512);
    for (int k = 0; k < 64; k++) {
        pass2_step<<<32, blk, 0, stream>>>(xb + (long)k * 16 * 512, A64T,
                                           G + (long)k * 16 * 512,
                                           xb + (long)(k + 1) * 16 * 512);
    }
    scatter_bounds<<<2080, blk, 0, stream>>>(xb, states);

    // ---- Phase 7 (pass 3): within-chunk scans from true boundaries ----
    {
        float* pin = xb;
        float* pout = Z0;
        for (int i = 0; i < 63; i++) {
            step_mfma<<<dim3(32, 8), blk, 0, stream>>>(pin, Ahig, Alog, Bu, i, pout, states);
            pin = pout;
            pout = (pin == Z0) ? Z1 : Z0;
        }
    }

    // ---- Phase 8: out = pre_states @ C^T + kscale*(u @ K22^T) ----
    mfma_nt<true, false><<<dim3(512, 2), blk, 0, stream>>>(65536, 256, 512,
        states, 512, Cmat, 512, out, 256, nullptr);
    mfma_nt<false, true><<<dim3(512, 2), blk, 0, stream>>>(65536, 256, 256,
        u, 256, Kraw + (long)512 * 768 + 512, 768, out, 256, &sc->kscale);
}